// Round 1
// baseline (220.692 us; speedup 1.0000x reference)
//
#include <hip/hip_runtime.h>
#include <hip/hip_bf16.h>

// Problem constants (derived from in_sizes at launch, but sized for):
//   n=10000 nodes, a=512, b=256, E=320000 edges.

// ---------------------------------------------------------------------------
// q = W @ emb_w   (q[k] = sum_j W[k][j] * emb_w[j]), K rows, Nb=256 cols.
// One wave per row k; 64 lanes x float4 = 256 cols.
__global__ __launch_bounds__(256) void k_q(const float* __restrict__ W,
                                           const float* __restrict__ emb_w,
                                           float* __restrict__ q, int K, int Nb) {
    int wave = threadIdx.x >> 6;
    int lane = threadIdx.x & 63;
    int k = blockIdx.x * 4 + wave;
    if (k >= K) return;
    float4 w4 = *(const float4*)&W[(size_t)k * Nb + lane * 4];
    float4 e4 = *(const float4*)&emb_w[lane * 4];
    float s = w4.x * e4.x + w4.y * e4.y + w4.z * e4.z + w4.w * e4.w;
    #pragma unroll
    for (int d = 32; d; d >>= 1) s += __shfl_down(s, d);
    if (lane == 0) q[k] = s;
}

// p[i] = (dot(H[i,:], q) + emb_b) * rv   -- f32-exact path for the routing cond
__global__ __launch_bounds__(256) void k_p(const float* __restrict__ H,
                                           const float* __restrict__ q,
                                           const float* __restrict__ emb_b,
                                           const float* __restrict__ rv,
                                           float* __restrict__ p, int M, int K) {
    int wave = threadIdx.x >> 6;
    int lane = threadIdx.x & 63;
    int i = blockIdx.x * 4 + wave;
    if (i >= M) return;
    const float* h = H + (size_t)i * K;
    float s = 0.f;
    for (int o = 0; o < K; o += 256) {  // K=512 -> 2 iters, 64 lanes x float4
        float4 h4 = *(const float4*)&h[o + lane * 4];
        float4 q4 = *(const float4*)&q[o + lane * 4];
        s += h4.x * q4.x + h4.y * q4.y + h4.z * q4.z + h4.w * q4.w;
    }
    #pragma unroll
    for (int d = 32; d; d >>= 1) s += __shfl_down(s, d);
    if (lane == 0) p[i] = (s + emb_b[0]) * rv[0];
}

// ---------------------------------------------------------------------------
// HW = H @ W  (f32 vector GEMM, 64x64 tile, 4x4 per thread)
#define BM 64
#define BN 64
#define BK 32
__global__ __launch_bounds__(256) void k_gemm(const float* __restrict__ A,
                                              const float* __restrict__ B,
                                              float* __restrict__ C,
                                              int M, int N, int K) {
    __shared__ float As[BK][BM + 4];  // +4 keeps float4 alignment, breaks bank stride
    __shared__ float Bs[BK][BN];
    int tid = threadIdx.x;
    int tx = tid & 15, ty = tid >> 4;
    int rowBase = blockIdx.x * BM;
    int colBase = blockIdx.y * BN;
    float acc[4][4] = {};
    for (int k0 = 0; k0 < K; k0 += BK) {
        // stage A tile (64 rows x 32 k), transposed into As[k][m]
        {
            int r = tid >> 3;
            int kq = (tid & 7) * 4;
            #pragma unroll
            for (int h = 0; h < 2; ++h) {
                int rr = r + h * 32;
                int gRow = rowBase + rr;
                float4 v = make_float4(0.f, 0.f, 0.f, 0.f);
                if (gRow < M) v = *(const float4*)&A[(size_t)gRow * K + k0 + kq];
                As[kq + 0][rr] = v.x;
                As[kq + 1][rr] = v.y;
                As[kq + 2][rr] = v.z;
                As[kq + 3][rr] = v.w;
            }
        }
        // stage B tile (32 k x 64 cols), direct float4
        {
            int r = tid >> 4;
            int cq = (tid & 15) * 4;
            #pragma unroll
            for (int h = 0; h < 2; ++h) {
                int kk = r + h * 16;
                float4 v = *(const float4*)&B[(size_t)(k0 + kk) * N + colBase + cq];
                *(float4*)&Bs[kk][cq] = v;
            }
        }
        __syncthreads();
        #pragma unroll
        for (int kk = 0; kk < BK; ++kk) {
            float4 a4 = *(const float4*)&As[kk][ty * 4];
            float4 b4 = *(const float4*)&Bs[kk][tx * 4];
            float av[4] = {a4.x, a4.y, a4.z, a4.w};
            float bv[4] = {b4.x, b4.y, b4.z, b4.w};
            #pragma unroll
            for (int i = 0; i < 4; ++i)
                #pragma unroll
                for (int j = 0; j < 4; ++j)
                    acc[i][j] += av[i] * bv[j];
        }
        __syncthreads();
    }
    #pragma unroll
    for (int i = 0; i < 4; ++i) {
        int gRow = rowBase + ty * 4 + i;
        if (gRow < M) {
            float4 o = make_float4(acc[i][0], acc[i][1], acc[i][2], acc[i][3]);
            *(float4*)&C[(size_t)gRow * N + colBase + tx * 4] = o;
        }
    }
}

// ---------------------------------------------------------------------------
// CSR build: count -> scan -> fill
__global__ __launch_bounds__(256) void k_count(const int* __restrict__ st,
                                               int* __restrict__ cnt, int E) {
    int e = blockIdx.x * blockDim.x + threadIdx.x;
    if (e >= E) return;
    int u = st[e], v = st[E + e];
    atomicAdd(&cnt[u], 1);   // row u always receives one message
    atomicAdd(&cnt[v], 1);   // row v always receives one message
}

__global__ __launch_bounds__(256) void k_scan(const int* __restrict__ cnt,
                                              int* __restrict__ offsets,
                                              int* __restrict__ cursor, int n) {
    __shared__ int s[256];
    int t = threadIdx.x;
    int chunk = (n + 255) / 256;
    int beg = t * chunk;
    int end = min(beg + chunk, n);
    int sum = 0;
    for (int i = beg; i < end; ++i) sum += cnt[i];
    s[t] = sum;
    __syncthreads();
    // Hillis-Steele inclusive scan over 256 partials
    for (int d = 1; d < 256; d <<= 1) {
        int val = (t >= d) ? s[t - d] : 0;
        __syncthreads();
        s[t] += val;
        __syncthreads();
    }
    int run = (t == 0) ? 0 : s[t - 1];  // exclusive prefix
    for (int i = beg; i < end; ++i) {
        offsets[i] = run;
        cursor[i] = run;
        run += cnt[i];
    }
    if (t == 255) offsets[n] = run;
}

__global__ __launch_bounds__(256) void k_fill(const int* __restrict__ st,
                                              const float* __restrict__ p,
                                              int* __restrict__ cursor,
                                              int* __restrict__ colidx, int E) {
    int e = blockIdx.x * blockDim.x + threadIdx.x;
    if (e >= E) return;
    int u = st[e], v = st[E + e];
    float pu = p[u], pv = p[v];
    bool cond = pu > pv;
    int c0 = cond ? v : u;  // message source for row u
    int c1 = cond ? u : v;  // message source for row v
    int p0 = atomicAdd(&cursor[u], 1);
    colidx[p0] = c0;
    int p1 = atomicAdd(&cursor[v], 1);
    colidx[p1] = c1;
}

// ---------------------------------------------------------------------------
// out[r,:] = HW[r,:] + bias + sum_{j in CSR[r]} HW[colidx[j],:]
__global__ __launch_bounds__(256) void k_gather(const float* __restrict__ HW,
                                                const float* __restrict__ bias,
                                                const int* __restrict__ offsets,
                                                const int* __restrict__ colidx,
                                                float* __restrict__ out, int N) {
    __shared__ int sc[256];
    int r = blockIdx.x;
    int c = threadIdx.x;
    float acc0 = HW[(size_t)r * N + c] + bias[c];
    float acc1 = 0.f, acc2 = 0.f, acc3 = 0.f;
    int beg = offsets[r], end = offsets[r + 1];
    for (int j0 = beg; j0 < end; j0 += 256) {
        int m = min(256, end - j0);
        __syncthreads();
        if (c < m) sc[c] = colidx[j0 + c];
        __syncthreads();
        int t = 0;
        for (; t + 4 <= m; t += 4) {
            acc0 += HW[(size_t)sc[t]     * N + c];
            acc1 += HW[(size_t)sc[t + 1] * N + c];
            acc2 += HW[(size_t)sc[t + 2] * N + c];
            acc3 += HW[(size_t)sc[t + 3] * N + c];
        }
        for (; t < m; ++t) acc0 += HW[(size_t)sc[t] * N + c];
    }
    out[(size_t)r * N + c] = (acc0 + acc1) + (acc2 + acc3);
}

// ---------------------------------------------------------------------------
extern "C" void kernel_launch(void* const* d_in, const int* in_sizes, int n_in,
                              void* d_out, int out_size, void* d_ws, size_t ws_size,
                              hipStream_t stream) {
    const int*   st    = (const int*)d_in[0];    // structure [2,E] int32
    const float* H     = (const float*)d_in[1];  // [M,K]
    const float* W     = (const float*)d_in[2];  // [K,N]
    const float* bias  = (const float*)d_in[3];  // [N]
    const float* emb_w = (const float*)d_in[4];  // [N,1]
    const float* emb_b = (const float*)d_in[5];  // [1]
    const float* rv    = (const float*)d_in[6];  // [1]
    float* out = (float*)d_out;

    const int E = in_sizes[0] / 2;       // 320000
    const int N = in_sizes[3];           // 256
    const int K = in_sizes[2] / N;       // 512
    const int M = in_sizes[1] / K;       // 10000

    // workspace layout (256B-aligned slabs)
    char* ws = (char*)d_ws;
    size_t off = 0;
    auto alloc = [&](size_t bytes) -> char* {
        char* ptr = ws + off;
        off = (off + bytes + 255) & ~(size_t)255;
        return ptr;
    };
    float* q       = (float*)alloc((size_t)K * 4);
    float* p       = (float*)alloc((size_t)M * 4);
    float* HW      = (float*)alloc((size_t)M * N * 4);
    int*   cnt     = (int*)alloc((size_t)M * 4);
    int*   offsets = (int*)alloc((size_t)(M + 1) * 4);
    int*   cursor  = (int*)alloc((size_t)M * 4);
    int*   colidx  = (int*)alloc((size_t)2 * E * 4);
    (void)ws_size; (void)n_in; (void)out_size;

    hipMemsetAsync(cnt, 0, (size_t)M * 4, stream);

    k_q<<<(K + 3) / 4, 256, 0, stream>>>(W, emb_w, q, K, N);
    k_p<<<(M + 3) / 4, 256, 0, stream>>>(H, q, emb_b, rv, p, M, K);
    dim3 ggrid((M + BM - 1) / BM, N / BN);
    k_gemm<<<ggrid, 256, 0, stream>>>(H, W, HW, M, N, K);
    k_count<<<(E + 255) / 256, 256, 0, stream>>>(st, cnt, E);
    k_scan<<<1, 256, 0, stream>>>(cnt, offsets, cursor, M);
    k_fill<<<(E + 255) / 256, 256, 0, stream>>>(st, p, cursor, colidx, E);
    k_gather<<<M, 256, 0, stream>>>(HW, bias, offsets, colidx, out, N);
}

// Round 2
// 175.997 us; speedup vs baseline: 1.2540x; 1.2540x over previous
//
#include <hip/hip_runtime.h>
#include <hip/hip_bf16.h>

// n=10000 nodes, a=K=512, b=N=256, E=320000 edges.

typedef __attribute__((ext_vector_type(8))) short bf16x8;
typedef __attribute__((ext_vector_type(4))) float f32x4;

__device__ inline ushort f2bf(float f) {
    uint b = __float_as_uint(f);
    return (ushort)((b + 0x7FFFu + ((b >> 16) & 1u)) >> 16);  // RNE
}
__device__ inline float bf2f(ushort u) { return __uint_as_float((uint)u << 16); }

// ---------------------------------------------------------------------------
// q = W @ emb_w  (f32, exact path for the routing condition)
__global__ __launch_bounds__(256) void k_q(const float* __restrict__ W,
                                           const float* __restrict__ emb_w,
                                           float* __restrict__ q, int K, int Nb) {
    int wave = threadIdx.x >> 6;
    int lane = threadIdx.x & 63;
    int k = blockIdx.x * 4 + wave;
    if (k >= K) return;
    float4 w4 = *(const float4*)&W[(size_t)k * Nb + lane * 4];
    float4 e4 = *(const float4*)&emb_w[lane * 4];
    float s = w4.x * e4.x + w4.y * e4.y + w4.z * e4.z + w4.w * e4.w;
    #pragma unroll
    for (int d = 32; d; d >>= 1) s += __shfl_down(s, d);
    if (lane == 0) q[k] = s;
}

// W[k][n] f32 -> Wt[n][k] bf16  (transpose + cast; tiny: 512x256)
__global__ __launch_bounds__(256) void k_wt(const float* __restrict__ W,
                                            ushort* __restrict__ Wt, int K, int N) {
    __shared__ float ts[32][33];
    int x = threadIdx.x & 31, y = threadIdx.x >> 5;  // 32x8
    int k0 = blockIdx.x * 32, n0 = blockIdx.y * 32;
    #pragma unroll
    for (int i = 0; i < 4; ++i) {
        int kk = y + i * 8;
        ts[kk][x] = W[(size_t)(k0 + kk) * N + n0 + x];
    }
    __syncthreads();
    #pragma unroll
    for (int i = 0; i < 4; ++i) {
        int nn = y + i * 8;
        Wt[(size_t)(n0 + nn) * K + k0 + x] = f2bf(ts[x][nn]);
    }
}

// Fused: Hb = bf16(H)  AND  p[i] = (dot(H[i,:], q) + emb_b) * rv  (f32-exact)
__global__ __launch_bounds__(256) void k_hp(const float* __restrict__ H,
                                            const float* __restrict__ q,
                                            const float* __restrict__ emb_b,
                                            const float* __restrict__ rv,
                                            ushort* __restrict__ Hb,
                                            float* __restrict__ p, int M, int K) {
    int wid = threadIdx.x >> 6, lane = threadIdx.x & 63;
    int i = blockIdx.x * 4 + wid;
    if (i >= M) return;
    const float* h = H + (size_t)i * K;
    float s = 0.f;
    for (int o = lane * 8; o < K; o += 512) {
        float4 a = *(const float4*)&h[o];
        float4 b = *(const float4*)&h[o + 4];
        float4 qa = *(const float4*)&q[o];
        float4 qb = *(const float4*)&q[o + 4];
        s += a.x * qa.x + a.y * qa.y + a.z * qa.z + a.w * qa.w
           + b.x * qb.x + b.y * qb.y + b.z * qb.z + b.w * qb.w;
        ushort u[8] = {f2bf(a.x), f2bf(a.y), f2bf(a.z), f2bf(a.w),
                       f2bf(b.x), f2bf(b.y), f2bf(b.z), f2bf(b.w)};
        *(int4*)&Hb[(size_t)i * K + o] = *(int4*)u;
    }
    #pragma unroll
    for (int d = 32; d; d >>= 1) s += __shfl_down(s, d);
    if (lane == 0) p[i] = (s + emb_b[0]) * rv[0];
}

// ---------------------------------------------------------------------------
// HW = H @ W via bf16 MFMA. 128x128 tile, 4 waves, each wave 64x64 (4x4 frags
// of 16x16x32). LDS rows padded to 40 shorts (80B) -> conflict-free b128.
__global__ __launch_bounds__(256) void k_mm(const ushort* __restrict__ Hb,
                                            const ushort* __restrict__ Wt,
                                            float* __restrict__ HW,
                                            ushort* __restrict__ HWb,
                                            int M, int N, int K) {
    __shared__ ushort As[128][40];
    __shared__ ushort Bs[128][40];
    int tid = threadIdx.x;
    int wid = tid >> 6, lane = tid & 63;
    int m0 = blockIdx.x * 128, n0 = blockIdx.y * 128;
    int wm = (wid >> 1) * 64, wn = (wid & 1) * 64;
    int frow = lane & 15, fg = (lane >> 4) * 8;
    f32x4 acc[4][4] = {};
    for (int k0 = 0; k0 < K; k0 += 32) {
        #pragma unroll
        for (int h = 0; h < 2; ++h) {
            int chunk = tid + 256 * h;
            int row = chunk >> 2, kc = (chunk & 3) * 8;
            int gr = m0 + row;
            int4 va = make_int4(0, 0, 0, 0);
            if (gr < M) va = *(const int4*)&Hb[(size_t)gr * K + k0 + kc];
            *(int4*)&As[row][kc] = va;
            int4 vb = *(const int4*)&Wt[(size_t)(n0 + row) * K + k0 + kc];
            *(int4*)&Bs[row][kc] = vb;
        }
        __syncthreads();
        bf16x8 av[4], bv[4];
        #pragma unroll
        for (int i = 0; i < 4; ++i)
            av[i] = *(const bf16x8*)&As[wm + i * 16 + frow][fg];
        #pragma unroll
        for (int j = 0; j < 4; ++j)
            bv[j] = *(const bf16x8*)&Bs[wn + j * 16 + frow][fg];
        #pragma unroll
        for (int i = 0; i < 4; ++i)
            #pragma unroll
            for (int j = 0; j < 4; ++j)
                acc[i][j] = __builtin_amdgcn_mfma_f32_16x16x32_bf16(av[i], bv[j], acc[i][j], 0, 0, 0);
        __syncthreads();
    }
    // epilogue: C/D map col=lane&15, row=(lane>>4)*4+r  [verified m89/m91]
    int orow = (lane >> 4) * 4, ocol = lane & 15;
    #pragma unroll
    for (int i = 0; i < 4; ++i) {
        #pragma unroll
        for (int rr = 0; rr < 4; ++rr) {
            int grow = m0 + wm + i * 16 + orow + rr;
            if (grow < M) {
                #pragma unroll
                for (int j = 0; j < 4; ++j) {
                    float vv = acc[i][j][rr];
                    int gcol = n0 + wn + j * 16 + ocol;
                    HW[(size_t)grow * N + gcol] = vv;
                    HWb[(size_t)grow * N + gcol] = f2bf(vv);
                }
            }
        }
    }
}

// ---------------------------------------------------------------------------
// CSR build: count -> scan -> fill
__global__ __launch_bounds__(256) void k_count(const int* __restrict__ st,
                                               int* __restrict__ cnt, int E) {
    int e = blockIdx.x * blockDim.x + threadIdx.x;
    if (e >= E) return;
    int u = st[e], v = st[E + e];
    atomicAdd(&cnt[u], 1);
    atomicAdd(&cnt[v], 1);
}

__global__ __launch_bounds__(256) void k_scan(const int* __restrict__ cnt,
                                              int* __restrict__ offsets,
                                              int* __restrict__ cursor, int n) {
    __shared__ int s[256];
    int t = threadIdx.x;
    int chunk = (n + 255) / 256;
    int beg = t * chunk;
    int end = min(beg + chunk, n);
    int sum = 0;
    for (int i = beg; i < end; ++i) sum += cnt[i];
    s[t] = sum;
    __syncthreads();
    for (int d = 1; d < 256; d <<= 1) {
        int val = (t >= d) ? s[t - d] : 0;
        __syncthreads();
        s[t] += val;
        __syncthreads();
    }
    int run = (t == 0) ? 0 : s[t - 1];
    for (int i = beg; i < end; ++i) {
        offsets[i] = run;
        cursor[i] = run;
        run += cnt[i];
    }
    if (t == 255) offsets[n] = run;
}

__global__ __launch_bounds__(256) void k_fill(const int* __restrict__ st,
                                              const float* __restrict__ p,
                                              int* __restrict__ cursor,
                                              int* __restrict__ colidx, int E) {
    int e = blockIdx.x * blockDim.x + threadIdx.x;
    if (e >= E) return;
    int u = st[e], v = st[E + e];
    bool cond = p[u] > p[v];
    int c0 = cond ? v : u;
    int c1 = cond ? u : v;
    int p0 = atomicAdd(&cursor[u], 1);
    colidx[p0] = c0;
    int p1 = atomicAdd(&cursor[v], 1);
    colidx[p1] = c1;
}

// ---------------------------------------------------------------------------
// out[r,:] = HW[r,:] + bias + sum_j bf2f(HWb[colidx[j],:])
// 1 row/block, 4 waves partition messages, ushort4 (8B/lane) x unroll 4.
__global__ __launch_bounds__(256) void k_gather(const float* __restrict__ HW,
                                                const ushort* __restrict__ HWb,
                                                const float* __restrict__ bias,
                                                const int* __restrict__ offs,
                                                const int* __restrict__ colidx,
                                                float* __restrict__ out, int N) {
    __shared__ float red[4][256];
    int r = blockIdx.x;
    int wid = threadIdx.x >> 6, lane = threadIdx.x & 63;
    int beg = offs[r], end = offs[r + 1];
    float a0 = 0.f, a1 = 0.f, a2 = 0.f, a3 = 0.f;
    int j = beg + wid;
    for (; j + 12 < end; j += 16) {
        int c0 = colidx[j], c1 = colidx[j + 4], c2 = colidx[j + 8], c3 = colidx[j + 12];
        ushort4 m0 = *(const ushort4*)&HWb[(size_t)c0 * N + lane * 4];
        ushort4 m1 = *(const ushort4*)&HWb[(size_t)c1 * N + lane * 4];
        ushort4 m2 = *(const ushort4*)&HWb[(size_t)c2 * N + lane * 4];
        ushort4 m3 = *(const ushort4*)&HWb[(size_t)c3 * N + lane * 4];
        a0 += (bf2f(m0.x) + bf2f(m1.x)) + (bf2f(m2.x) + bf2f(m3.x));
        a1 += (bf2f(m0.y) + bf2f(m1.y)) + (bf2f(m2.y) + bf2f(m3.y));
        a2 += (bf2f(m0.z) + bf2f(m1.z)) + (bf2f(m2.z) + bf2f(m3.z));
        a3 += (bf2f(m0.w) + bf2f(m1.w)) + (bf2f(m2.w) + bf2f(m3.w));
    }
    for (; j < end; j += 4) {
        int c = colidx[j];
        ushort4 m = *(const ushort4*)&HWb[(size_t)c * N + lane * 4];
        a0 += bf2f(m.x); a1 += bf2f(m.y); a2 += bf2f(m.z); a3 += bf2f(m.w);
    }
    *(float4*)&red[wid][lane * 4] = make_float4(a0, a1, a2, a3);
    __syncthreads();
    int c = threadIdx.x;
    float s = (red[0][c] + red[1][c]) + (red[2][c] + red[3][c]);
    out[(size_t)r * N + c] = HW[(size_t)r * N + c] + bias[c] + s;
}

// ---------------------------------------------------------------------------
extern "C" void kernel_launch(void* const* d_in, const int* in_sizes, int n_in,
                              void* d_out, int out_size, void* d_ws, size_t ws_size,
                              hipStream_t stream) {
    const int*   st    = (const int*)d_in[0];
    const float* H     = (const float*)d_in[1];
    const float* W     = (const float*)d_in[2];
    const float* bias  = (const float*)d_in[3];
    const float* emb_w = (const float*)d_in[4];
    const float* emb_b = (const float*)d_in[5];
    const float* rv    = (const float*)d_in[6];
    float* out = (float*)d_out;

    const int E = in_sizes[0] / 2;       // 320000
    const int N = in_sizes[3];           // 256
    const int K = in_sizes[2] / N;       // 512
    const int M = in_sizes[1] / K;       // 10000

    char* ws = (char*)d_ws;
    size_t off = 0;
    auto alloc = [&](size_t bytes) -> char* {
        char* ptr = ws + off;
        off = (off + bytes + 255) & ~(size_t)255;
        return ptr;
    };
    float*  q       = (float*)alloc((size_t)K * 4);
    float*  p       = (float*)alloc((size_t)M * 4);
    float*  HW      = (float*)alloc((size_t)M * N * 4);
    ushort* HWb     = (ushort*)alloc((size_t)M * N * 2);
    ushort* Hb      = (ushort*)alloc((size_t)M * K * 2);
    ushort* Wt      = (ushort*)alloc((size_t)K * N * 2);
    int*    cnt     = (int*)alloc((size_t)M * 4);
    int*    offsets = (int*)alloc((size_t)(M + 1) * 4);
    int*    cursor  = (int*)alloc((size_t)M * 4);
    int*    colidx  = (int*)alloc((size_t)2 * E * 4);
    (void)ws_size; (void)n_in; (void)out_size;

    hipMemsetAsync(cnt, 0, (size_t)M * 4, stream);

    k_q<<<(K + 3) / 4, 256, 0, stream>>>(W, emb_w, q, K, N);
    k_wt<<<dim3(K / 32, N / 32), 256, 0, stream>>>(W, Wt, K, N);
    k_hp<<<(M + 3) / 4, 256, 0, stream>>>(H, q, emb_b, rv, Hb, p, M, K);
    k_count<<<(E + 255) / 256, 256, 0, stream>>>(st, cnt, E);
    k_scan<<<1, 256, 0, stream>>>(cnt, offsets, cursor, M);
    k_fill<<<(E + 255) / 256, 256, 0, stream>>>(st, p, cursor, colidx, E);
    k_mm<<<dim3((M + 127) / 128, N / 128), 256, 0, stream>>>(Hb, Wt, HW, HWb, M, N, K);
    k_gather<<<M, 256, 0, stream>>>(HW, HWb, bias, offsets, colidx, out, N);
}

// Round 3
// 169.771 us; speedup vs baseline: 1.2999x; 1.0367x over previous
//
#include <hip/hip_runtime.h>
#include <hip/hip_bf16.h>

// n=10000 nodes, a=K=512, b=N=256, E=320000 edges.

typedef __attribute__((ext_vector_type(8))) short bf16x8;
typedef __attribute__((ext_vector_type(4))) float f32x4;

__device__ inline ushort f2bf(float f) {
    uint b = __float_as_uint(f);
    return (ushort)((b + 0x7FFFu + ((b >> 16) & 1u)) >> 16);  // RNE
}
__device__ inline float bf2f(ushort u) { return __uint_as_float((uint)u << 16); }

// ---------------------------------------------------------------------------
// Fused prelude (one launch):
//   blocks [0, K/4):              q = W @ emb_w   (f32-exact routing path)
//   blocks [K/4, K/4 + K/32*N/32): Wt[n][k] = bf16(W[k][n])
//   remaining blocks:              cnt[i] = 0
__global__ __launch_bounds__(256) void k_prep(const float* __restrict__ W,
                                              const float* __restrict__ emb_w,
                                              float* __restrict__ q,
                                              ushort* __restrict__ Wt,
                                              int* __restrict__ cnt,
                                              int K, int N, int M) {
    int b = blockIdx.x;
    int nq = K / 4;                       // 128 q-blocks (4 waves each)
    int nt = (K / 32) * (N / 32);         // 128 transpose blocks
    if (b < nq) {
        int wave = threadIdx.x >> 6;
        int lane = threadIdx.x & 63;
        int k = b * 4 + wave;
        float4 w4 = *(const float4*)&W[(size_t)k * N + lane * 4];
        float4 e4 = *(const float4*)&emb_w[lane * 4];
        float s = w4.x * e4.x + w4.y * e4.y + w4.z * e4.z + w4.w * e4.w;
        #pragma unroll
        for (int d = 32; d; d >>= 1) s += __shfl_down(s, d);
        if (lane == 0) q[k] = s;
    } else if (b < nq + nt) {
        __shared__ float ts[32][33];
        int idx = b - nq;
        int k0 = (idx % (K / 32)) * 32;
        int n0 = (idx / (K / 32)) * 32;
        int x = threadIdx.x & 31, y = threadIdx.x >> 5;  // 32x8
        #pragma unroll
        for (int i = 0; i < 4; ++i) {
            int kk = y + i * 8;
            ts[kk][x] = W[(size_t)(k0 + kk) * N + n0 + x];
        }
        __syncthreads();
        #pragma unroll
        for (int i = 0; i < 4; ++i) {
            int nn = y + i * 8;
            Wt[(size_t)(n0 + nn) * K + k0 + x] = f2bf(ts[x][nn]);
        }
    } else {
        int i = (b - nq - nt) * 256 + threadIdx.x;
        if (i < M) cnt[i] = 0;
    }
}

// Fused: Hb = bf16(H)  AND  p[i] = (dot(H[i,:], q) + emb_b) * rv  (f32-exact)
__global__ __launch_bounds__(256) void k_hp(const float* __restrict__ H,
                                            const float* __restrict__ q,
                                            const float* __restrict__ emb_b,
                                            const float* __restrict__ rv,
                                            ushort* __restrict__ Hb,
                                            float* __restrict__ p, int M, int K) {
    int wid = threadIdx.x >> 6, lane = threadIdx.x & 63;
    int i = blockIdx.x * 4 + wid;
    if (i >= M) return;
    const float* h = H + (size_t)i * K;
    float s = 0.f;
    for (int o = lane * 8; o < K; o += 512) {
        float4 a = *(const float4*)&h[o];
        float4 b = *(const float4*)&h[o + 4];
        float4 qa = *(const float4*)&q[o];
        float4 qb = *(const float4*)&q[o + 4];
        s += a.x * qa.x + a.y * qa.y + a.z * qa.z + a.w * qa.w
           + b.x * qb.x + b.y * qb.y + b.z * qb.z + b.w * qb.w;
        ushort u[8] = {f2bf(a.x), f2bf(a.y), f2bf(a.z), f2bf(a.w),
                       f2bf(b.x), f2bf(b.y), f2bf(b.z), f2bf(b.w)};
        *(int4*)&Hb[(size_t)i * K + o] = *(int4*)u;
    }
    #pragma unroll
    for (int d = 32; d; d >>= 1) s += __shfl_down(s, d);
    if (lane == 0) p[i] = (s + emb_b[0]) * rv[0];
}

// ---------------------------------------------------------------------------
// HWb = bf16(H @ W) via bf16 MFMA. 128x128 tile, 4 waves x (4x4 frags of
// 16x16x32). LDS rows padded to 40 shorts -> conflict-free ds_read_b128.
__global__ __launch_bounds__(256) void k_mm(const ushort* __restrict__ Hb,
                                            const ushort* __restrict__ Wt,
                                            ushort* __restrict__ HWb,
                                            int M, int N, int K) {
    __shared__ ushort As[128][40];
    __shared__ ushort Bs[128][40];
    int tid = threadIdx.x;
    int wid = tid >> 6, lane = tid & 63;
    int m0 = blockIdx.x * 128, n0 = blockIdx.y * 128;
    int wm = (wid >> 1) * 64, wn = (wid & 1) * 64;
    int frow = lane & 15, fg = (lane >> 4) * 8;
    f32x4 acc[4][4] = {};
    for (int k0 = 0; k0 < K; k0 += 32) {
        #pragma unroll
        for (int h = 0; h < 2; ++h) {
            int chunk = tid + 256 * h;
            int row = chunk >> 2, kc = (chunk & 3) * 8;
            int gr = m0 + row;
            int4 va = make_int4(0, 0, 0, 0);
            if (gr < M) va = *(const int4*)&Hb[(size_t)gr * K + k0 + kc];
            *(int4*)&As[row][kc] = va;
            int4 vb = *(const int4*)&Wt[(size_t)(n0 + row) * K + k0 + kc];
            *(int4*)&Bs[row][kc] = vb;
        }
        __syncthreads();
        bf16x8 av[4], bv[4];
        #pragma unroll
        for (int i = 0; i < 4; ++i)
            av[i] = *(const bf16x8*)&As[wm + i * 16 + frow][fg];
        #pragma unroll
        for (int j = 0; j < 4; ++j)
            bv[j] = *(const bf16x8*)&Bs[wn + j * 16 + frow][fg];
        #pragma unroll
        for (int i = 0; i < 4; ++i)
            #pragma unroll
            for (int j = 0; j < 4; ++j)
                acc[i][j] = __builtin_amdgcn_mfma_f32_16x16x32_bf16(av[i], bv[j], acc[i][j], 0, 0, 0);
        __syncthreads();
    }
    // C/D map: col=lane&15, row=(lane>>4)*4+rr  [verified m89/m91]
    int orow = (lane >> 4) * 4, ocol = lane & 15;
    #pragma unroll
    for (int i = 0; i < 4; ++i) {
        #pragma unroll
        for (int rr = 0; rr < 4; ++rr) {
            int grow = m0 + wm + i * 16 + orow + rr;
            if (grow < M) {
                #pragma unroll
                for (int j = 0; j < 4; ++j) {
                    int gcol = n0 + wn + j * 16 + ocol;
                    HWb[(size_t)grow * N + gcol] = f2bf(acc[i][j][rr]);
                }
            }
        }
    }
}

// ---------------------------------------------------------------------------
// CSR build: count -> scan -> fill
__global__ __launch_bounds__(256) void k_count(const int* __restrict__ st,
                                               int* __restrict__ cnt, int E) {
    int e = blockIdx.x * blockDim.x + threadIdx.x;
    if (e >= E) return;
    int u = st[e], v = st[E + e];
    atomicAdd(&cnt[u], 1);
    atomicAdd(&cnt[v], 1);
}

__global__ __launch_bounds__(256) void k_scan(const int* __restrict__ cnt,
                                              int* __restrict__ offsets,
                                              int* __restrict__ cursor, int n) {
    __shared__ int s[256];
    int t = threadIdx.x;
    int chunk = (n + 255) / 256;
    int beg = t * chunk;
    int end = min(beg + chunk, n);
    int sum = 0;
    for (int i = beg; i < end; ++i) sum += cnt[i];
    s[t] = sum;
    __syncthreads();
    for (int d = 1; d < 256; d <<= 1) {
        int val = (t >= d) ? s[t - d] : 0;
        __syncthreads();
        s[t] += val;
        __syncthreads();
    }
    int run = (t == 0) ? 0 : s[t - 1];
    for (int i = beg; i < end; ++i) {
        offsets[i] = run;
        cursor[i] = run;
        run += cnt[i];
    }
    if (t == 255) offsets[n] = run;
}

__global__ __launch_bounds__(256) void k_fill(const int* __restrict__ st,
                                              const float* __restrict__ p,
                                              int* __restrict__ cursor,
                                              int* __restrict__ colidx, int E) {
    int e = blockIdx.x * blockDim.x + threadIdx.x;
    if (e >= E) return;
    int u = st[e], v = st[E + e];
    bool cond = p[u] > p[v];
    int c0 = cond ? v : u;
    int c1 = cond ? u : v;
    int p0 = atomicAdd(&cursor[u], 1);
    colidx[p0] = c0;
    int p1 = atomicAdd(&cursor[v], 1);
    colidx[p1] = c1;
}

// ---------------------------------------------------------------------------
// out[r,:] = bf2f(HWb[r,:]) + bias + sum_j bf2f(HWb[colidx[j],:])
// 1 row/block, 4 waves partition messages, ushort4 (8B/lane) x unroll 4.
__global__ __launch_bounds__(256) void k_gather(const ushort* __restrict__ HWb,
                                                const float* __restrict__ bias,
                                                const int* __restrict__ offs,
                                                const int* __restrict__ colidx,
                                                float* __restrict__ out, int N) {
    __shared__ float red[4][256];
    int r = blockIdx.x;
    int wid = threadIdx.x >> 6, lane = threadIdx.x & 63;
    int beg = offs[r], end = offs[r + 1];
    float a0 = 0.f, a1 = 0.f, a2 = 0.f, a3 = 0.f;
    int j = beg + wid;
    for (; j + 12 < end; j += 16) {
        int c0 = colidx[j], c1 = colidx[j + 4], c2 = colidx[j + 8], c3 = colidx[j + 12];
        ushort4 m0 = *(const ushort4*)&HWb[(size_t)c0 * N + lane * 4];
        ushort4 m1 = *(const ushort4*)&HWb[(size_t)c1 * N + lane * 4];
        ushort4 m2 = *(const ushort4*)&HWb[(size_t)c2 * N + lane * 4];
        ushort4 m3 = *(const ushort4*)&HWb[(size_t)c3 * N + lane * 4];
        a0 += (bf2f(m0.x) + bf2f(m1.x)) + (bf2f(m2.x) + bf2f(m3.x));
        a1 += (bf2f(m0.y) + bf2f(m1.y)) + (bf2f(m2.y) + bf2f(m3.y));
        a2 += (bf2f(m0.z) + bf2f(m1.z)) + (bf2f(m2.z) + bf2f(m3.z));
        a3 += (bf2f(m0.w) + bf2f(m1.w)) + (bf2f(m2.w) + bf2f(m3.w));
    }
    for (; j < end; j += 4) {
        int c = colidx[j];
        ushort4 m = *(const ushort4*)&HWb[(size_t)c * N + lane * 4];
        a0 += bf2f(m.x); a1 += bf2f(m.y); a2 += bf2f(m.z); a3 += bf2f(m.w);
    }
    *(float4*)&red[wid][lane * 4] = make_float4(a0, a1, a2, a3);
    __syncthreads();
    int c = threadIdx.x;
    float s = (red[0][c] + red[1][c]) + (red[2][c] + red[3][c]);
    out[(size_t)r * N + c] = bf2f(HWb[(size_t)r * N + c]) + bias[c] + s;
}

// ---------------------------------------------------------------------------
extern "C" void kernel_launch(void* const* d_in, const int* in_sizes, int n_in,
                              void* d_out, int out_size, void* d_ws, size_t ws_size,
                              hipStream_t stream) {
    const int*   st    = (const int*)d_in[0];
    const float* H     = (const float*)d_in[1];
    const float* W     = (const float*)d_in[2];
    const float* bias  = (const float*)d_in[3];
    const float* emb_w = (const float*)d_in[4];
    const float* emb_b = (const float*)d_in[5];
    const float* rv    = (const float*)d_in[6];
    float* out = (float*)d_out;

    const int E = in_sizes[0] / 2;       // 320000
    const int N = in_sizes[3];           // 256
    const int K = in_sizes[2] / N;       // 512
    const int M = in_sizes[1] / K;       // 10000

    char* ws = (char*)d_ws;
    size_t off = 0;
    auto alloc = [&](size_t bytes) -> char* {
        char* ptr = ws + off;
        off = (off + bytes + 255) & ~(size_t)255;
        return ptr;
    };
    float*  q       = (float*)alloc((size_t)K * 4);
    float*  p       = (float*)alloc((size_t)M * 4);
    ushort* HWb     = (ushort*)alloc((size_t)M * N * 2);
    ushort* Hb      = (ushort*)alloc((size_t)M * K * 2);
    ushort* Wt      = (ushort*)alloc((size_t)K * N * 2);
    int*    cnt     = (int*)alloc((size_t)M * 4);
    int*    offsets = (int*)alloc((size_t)(M + 1) * 4);
    int*    cursor  = (int*)alloc((size_t)M * 4);
    int*    colidx  = (int*)alloc((size_t)2 * E * 4);
    (void)ws_size; (void)n_in; (void)out_size;

    int nprep = K / 4 + (K / 32) * (N / 32) + (M + 255) / 256;
    k_prep<<<nprep, 256, 0, stream>>>(W, emb_w, q, Wt, cnt, K, N, M);
    k_hp<<<(M + 3) / 4, 256, 0, stream>>>(H, q, emb_b, rv, Hb, p, M, K);
    k_count<<<(E + 255) / 256, 256, 0, stream>>>(st, cnt, E);
    k_scan<<<1, 256, 0, stream>>>(cnt, offsets, cursor, M);
    k_fill<<<(E + 255) / 256, 256, 0, stream>>>(st, p, cursor, colidx, E);
    k_mm<<<dim3((M + 127) / 128, N / 128), 256, 0, stream>>>(Hb, Wt, HWb, M, N, K);
    k_gather<<<M, 256, 0, stream>>>(HWb, bias, offsets, colidx, out, N);
}

// Round 4
// 125.279 us; speedup vs baseline: 1.7616x; 1.3551x over previous
//
#include <hip/hip_runtime.h>
#include <hip/hip_bf16.h>

// n=M=10000 nodes, a=K=512, b=N=256, E=320000 edges.
// LDS histogram arrays are capped at M<=10240.

#define NB  256   // edge-partition blocks for hist/fill
#define TPB 512
#define MCAP 10240

typedef __attribute__((ext_vector_type(8))) short bf16x8;
typedef __attribute__((ext_vector_type(4))) float f32x4;

__device__ inline ushort f2bf(float f) {
    uint b = __float_as_uint(f);
    return (ushort)((b + 0x7FFFu + ((b >> 16) & 1u)) >> 16);  // RNE
}
__device__ inline float bf2f(ushort u) { return __uint_as_float((uint)u << 16); }

// ---------------------------------------------------------------------------
// Fused prelude: blocks [0,K/4): q = W @ emb_w (f32-exact routing path);
//                blocks [K/4, ...): Wt[n][k] = bf16(W[k][n])
__global__ __launch_bounds__(256) void k_prep(const float* __restrict__ W,
                                              const float* __restrict__ emb_w,
                                              float* __restrict__ q,
                                              ushort* __restrict__ Wt,
                                              int K, int N) {
    int b = blockIdx.x;
    int nq = K / 4;
    if (b < nq) {
        int wave = threadIdx.x >> 6;
        int lane = threadIdx.x & 63;
        int k = b * 4 + wave;
        float4 w4 = *(const float4*)&W[(size_t)k * N + lane * 4];
        float4 e4 = *(const float4*)&emb_w[lane * 4];
        float s = w4.x * e4.x + w4.y * e4.y + w4.z * e4.z + w4.w * e4.w;
        #pragma unroll
        for (int d = 32; d; d >>= 1) s += __shfl_down(s, d);
        if (lane == 0) q[k] = s;
    } else {
        __shared__ float ts[32][33];
        int idx = b - nq;
        int k0 = (idx % (K / 32)) * 32;
        int n0 = (idx / (K / 32)) * 32;
        int x = threadIdx.x & 31, y = threadIdx.x >> 5;  // 32x8
        #pragma unroll
        for (int i = 0; i < 4; ++i) {
            int kk = y + i * 8;
            ts[kk][x] = W[(size_t)(k0 + kk) * N + n0 + x];
        }
        __syncthreads();
        #pragma unroll
        for (int i = 0; i < 4; ++i) {
            int nn = y + i * 8;
            Wt[(size_t)(n0 + nn) * K + k0 + x] = f2bf(ts[x][nn]);
        }
    }
}

// Fused: Hb = bf16(H)  AND  p[i] = (dot(H[i,:], q) + emb_b) * rv  (f32-exact)
__global__ __launch_bounds__(256) void k_hp(const float* __restrict__ H,
                                            const float* __restrict__ q,
                                            const float* __restrict__ emb_b,
                                            const float* __restrict__ rv,
                                            ushort* __restrict__ Hb,
                                            float* __restrict__ p, int M, int K) {
    int wid = threadIdx.x >> 6, lane = threadIdx.x & 63;
    int i = blockIdx.x * 4 + wid;
    if (i >= M) return;
    const float* h = H + (size_t)i * K;
    float s = 0.f;
    for (int o = lane * 8; o < K; o += 512) {
        float4 a = *(const float4*)&h[o];
        float4 b = *(const float4*)&h[o + 4];
        float4 qa = *(const float4*)&q[o];
        float4 qb = *(const float4*)&q[o + 4];
        s += a.x * qa.x + a.y * qa.y + a.z * qa.z + a.w * qa.w
           + b.x * qb.x + b.y * qb.y + b.z * qb.z + b.w * qb.w;
        ushort u[8] = {f2bf(a.x), f2bf(a.y), f2bf(a.z), f2bf(a.w),
                       f2bf(b.x), f2bf(b.y), f2bf(b.z), f2bf(b.w)};
        *(int4*)&Hb[(size_t)i * K + o] = *(int4*)u;
    }
    #pragma unroll
    for (int d = 32; d; d >>= 1) s += __shfl_down(s, d);
    if (lane == 0) p[i] = (s + emb_b[0]) * rv[0];
}

// ---------------------------------------------------------------------------
// Per-block LDS histogram of edge endpoints; cross entries (cond true) packed
// in low 16 bits, self entries (cond false) in high 16 bits. No global atomics.
__global__ __launch_bounds__(TPB) void k_hist(const int* __restrict__ st,
                                              const float* __restrict__ p,
                                              uint* __restrict__ parthist,
                                              int E, int M) {
    __shared__ uint h[MCAP];
    for (int i = threadIdx.x; i < M; i += TPB) h[i] = 0;
    __syncthreads();
    int b = blockIdx.x;
    int epb = (E + NB - 1) / NB;
    int beg = b * epb, end = min(beg + epb, E);
    for (int e = beg + threadIdx.x; e < end; e += TPB) {
        int u = st[e], v = st[E + e];
        uint inc = (p[u] > p[v]) ? 1u : (1u << 16);
        atomicAdd(&h[u], inc);
        atomicAdd(&h[v], inc);
    }
    __syncthreads();
    for (int i = threadIdx.x; i < M; i += TPB)
        parthist[(size_t)b * M + i] = h[i];
}

// Per-row merge over blocks: in-place exclusive cross-prefix (blockbase),
// total cross count, and selfmul = 1 + selfdeg.
__global__ __launch_bounds__(256) void k_merge(uint* __restrict__ parthist,
                                               int* __restrict__ crosscnt,
                                               float* __restrict__ selfmul, int M) {
    int r = blockIdx.x * 256 + threadIdx.x;
    if (r >= M) return;
    uint crun = 0, srun = 0;
    for (int b = 0; b < NB; ++b) {
        uint v = parthist[(size_t)b * M + r];
        parthist[(size_t)b * M + r] = crun;   // exclusive cross prefix for block b
        crun += v & 0xFFFFu;
        srun += v >> 16;
    }
    crosscnt[r] = (int)crun;
    selfmul[r] = 1.0f + (float)srun;
}

__global__ __launch_bounds__(256) void k_scan(const int* __restrict__ cnt,
                                              int* __restrict__ offsets, int n) {
    __shared__ int s[256];
    int t = threadIdx.x;
    int chunk = (n + 255) / 256;
    int beg = t * chunk;
    int end = min(beg + chunk, n);
    int sum = 0;
    for (int i = beg; i < end; ++i) sum += cnt[i];
    s[t] = sum;
    __syncthreads();
    for (int d = 1; d < 256; d <<= 1) {
        int val = (t >= d) ? s[t - d] : 0;
        __syncthreads();
        s[t] += val;
        __syncthreads();
    }
    int run = (t == 0) ? 0 : s[t - 1];
    for (int i = beg; i < end; ++i) {
        offsets[i] = run;
        run += cnt[i];
    }
    if (t == 255) offsets[n] = run;
}

// Slot assignment with LDS cursors; only cross edges emit colidx entries.
__global__ __launch_bounds__(TPB) void k_fill2(const int* __restrict__ st,
                                               const float* __restrict__ p,
                                               const int* __restrict__ offsets,
                                               const uint* __restrict__ blockbase,
                                               int* __restrict__ colidx,
                                               int E, int M) {
    __shared__ int cur[MCAP];
    int b = blockIdx.x;
    for (int i = threadIdx.x; i < M; i += TPB)
        cur[i] = offsets[i] + (int)blockbase[(size_t)b * M + i];
    __syncthreads();
    int epb = (E + NB - 1) / NB;
    int beg = b * epb, end = min(beg + epb, E);
    for (int e = beg + threadIdx.x; e < end; e += TPB) {
        int u = st[e], v = st[E + e];
        if (p[u] > p[v]) {
            int su = atomicAdd(&cur[u], 1);
            colidx[su] = v;
            int sv = atomicAdd(&cur[v], 1);
            colidx[sv] = u;
        }
    }
}

// ---------------------------------------------------------------------------
// HWb = bf16(H @ W) via bf16 MFMA. 128x128 tile, 4 waves x (4x4 frags of
// 16x16x32). LDS rows padded to 40 shorts -> conflict-free ds_read_b128.
__global__ __launch_bounds__(256) void k_mm(const ushort* __restrict__ Hb,
                                            const ushort* __restrict__ Wt,
                                            ushort* __restrict__ HWb,
                                            int M, int N, int K) {
    __shared__ ushort As[128][40];
    __shared__ ushort Bs[128][40];
    int tid = threadIdx.x;
    int wid = tid >> 6, lane = tid & 63;
    int m0 = blockIdx.x * 128, n0 = blockIdx.y * 128;
    int wm = (wid >> 1) * 64, wn = (wid & 1) * 64;
    int frow = lane & 15, fg = (lane >> 4) * 8;
    f32x4 acc[4][4] = {};
    for (int k0 = 0; k0 < K; k0 += 32) {
        #pragma unroll
        for (int h = 0; h < 2; ++h) {
            int chunk = tid + 256 * h;
            int row = chunk >> 2, kc = (chunk & 3) * 8;
            int gr = m0 + row;
            int4 va = make_int4(0, 0, 0, 0);
            if (gr < M) va = *(const int4*)&Hb[(size_t)gr * K + k0 + kc];
            *(int4*)&As[row][kc] = va;
            int4 vb = *(const int4*)&Wt[(size_t)(n0 + row) * K + k0 + kc];
            *(int4*)&Bs[row][kc] = vb;
        }
        __syncthreads();
        bf16x8 av[4], bv[4];
        #pragma unroll
        for (int i = 0; i < 4; ++i)
            av[i] = *(const bf16x8*)&As[wm + i * 16 + frow][fg];
        #pragma unroll
        for (int j = 0; j < 4; ++j)
            bv[j] = *(const bf16x8*)&Bs[wn + j * 16 + frow][fg];
        #pragma unroll
        for (int i = 0; i < 4; ++i)
            #pragma unroll
            for (int j = 0; j < 4; ++j)
                acc[i][j] = __builtin_amdgcn_mfma_f32_16x16x32_bf16(av[i], bv[j], acc[i][j], 0, 0, 0);
        __syncthreads();
    }
    // C/D map: col=lane&15, row=(lane>>4)*4+rr  [verified m89/m91]
    int orow = (lane >> 4) * 4, ocol = lane & 15;
    #pragma unroll
    for (int i = 0; i < 4; ++i) {
        #pragma unroll
        for (int rr = 0; rr < 4; ++rr) {
            int grow = m0 + wm + i * 16 + orow + rr;
            if (grow < M) {
                #pragma unroll
                for (int j = 0; j < 4; ++j) {
                    int gcol = n0 + wn + j * 16 + ocol;
                    HWb[(size_t)grow * N + gcol] = f2bf(acc[i][j][rr]);
                }
            }
        }
    }
}

// ---------------------------------------------------------------------------
// out[r,:] = bf2f(HWb[r,:]) * selfmul[r] + bias + sum_j bf2f(HWb[colidx[j],:])
__global__ __launch_bounds__(256) void k_gather(const ushort* __restrict__ HWb,
                                                const float* __restrict__ bias,
                                                const float* __restrict__ selfmul,
                                                const int* __restrict__ offs,
                                                const int* __restrict__ colidx,
                                                float* __restrict__ out, int N) {
    __shared__ float red[4][256];
    int r = blockIdx.x;
    int wid = threadIdx.x >> 6, lane = threadIdx.x & 63;
    int beg = offs[r], end = offs[r + 1];
    float a0 = 0.f, a1 = 0.f, a2 = 0.f, a3 = 0.f;
    int j = beg + wid;
    for (; j + 12 < end; j += 16) {
        int c0 = colidx[j], c1 = colidx[j + 4], c2 = colidx[j + 8], c3 = colidx[j + 12];
        ushort4 m0 = *(const ushort4*)&HWb[(size_t)c0 * N + lane * 4];
        ushort4 m1 = *(const ushort4*)&HWb[(size_t)c1 * N + lane * 4];
        ushort4 m2 = *(const ushort4*)&HWb[(size_t)c2 * N + lane * 4];
        ushort4 m3 = *(const ushort4*)&HWb[(size_t)c3 * N + lane * 4];
        a0 += (bf2f(m0.x) + bf2f(m1.x)) + (bf2f(m2.x) + bf2f(m3.x));
        a1 += (bf2f(m0.y) + bf2f(m1.y)) + (bf2f(m2.y) + bf2f(m3.y));
        a2 += (bf2f(m0.z) + bf2f(m1.z)) + (bf2f(m2.z) + bf2f(m3.z));
        a3 += (bf2f(m0.w) + bf2f(m1.w)) + (bf2f(m2.w) + bf2f(m3.w));
    }
    for (; j < end; j += 4) {
        int c = colidx[j];
        ushort4 m = *(const ushort4*)&HWb[(size_t)c * N + lane * 4];
        a0 += bf2f(m.x); a1 += bf2f(m.y); a2 += bf2f(m.z); a3 += bf2f(m.w);
    }
    *(float4*)&red[wid][lane * 4] = make_float4(a0, a1, a2, a3);
    __syncthreads();
    int c = threadIdx.x;
    float s = (red[0][c] + red[1][c]) + (red[2][c] + red[3][c]);
    out[(size_t)r * N + c] = bf2f(HWb[(size_t)r * N + c]) * selfmul[r] + bias[c] + s;
}

// ---------------------------------------------------------------------------
extern "C" void kernel_launch(void* const* d_in, const int* in_sizes, int n_in,
                              void* d_out, int out_size, void* d_ws, size_t ws_size,
                              hipStream_t stream) {
    const int*   st    = (const int*)d_in[0];
    const float* H     = (const float*)d_in[1];
    const float* W     = (const float*)d_in[2];
    const float* bias  = (const float*)d_in[3];
    const float* emb_w = (const float*)d_in[4];
    const float* emb_b = (const float*)d_in[5];
    const float* rv    = (const float*)d_in[6];
    float* out = (float*)d_out;

    const int E = in_sizes[0] / 2;       // 320000
    const int N = in_sizes[3];           // 256
    const int K = in_sizes[2] / N;       // 512
    const int M = in_sizes[1] / K;       // 10000  (must be <= MCAP)

    char* ws = (char*)d_ws;
    size_t off = 0;
    auto alloc = [&](size_t bytes) -> char* {
        char* ptr = ws + off;
        off = (off + bytes + 255) & ~(size_t)255;
        return ptr;
    };
    float*  q        = (float*)alloc((size_t)K * 4);
    float*  p        = (float*)alloc((size_t)M * 4);
    ushort* HWb      = (ushort*)alloc((size_t)M * N * 2);
    ushort* Hb       = (ushort*)alloc((size_t)M * K * 2);
    ushort* Wt       = (ushort*)alloc((size_t)K * N * 2);
    uint*   parthist = (uint*)alloc((size_t)NB * M * 4);
    int*    crosscnt = (int*)alloc((size_t)M * 4);
    float*  selfmul  = (float*)alloc((size_t)M * 4);
    int*    offsets  = (int*)alloc((size_t)(M + 1) * 4);
    int*    colidx   = (int*)alloc((size_t)2 * E * 4);
    (void)ws_size; (void)n_in; (void)out_size;

    int nprep = K / 4 + (K / 32) * (N / 32);
    k_prep<<<nprep, 256, 0, stream>>>(W, emb_w, q, Wt, K, N);
    k_hp<<<(M + 3) / 4, 256, 0, stream>>>(H, q, emb_b, rv, Hb, p, M, K);
    k_hist<<<NB, TPB, 0, stream>>>(st, p, parthist, E, M);
    k_merge<<<(M + 255) / 256, 256, 0, stream>>>(parthist, crosscnt, selfmul, M);
    k_scan<<<1, 256, 0, stream>>>(crosscnt, offsets, M);
    k_fill2<<<NB, TPB, 0, stream>>>(st, p, offsets, parthist, colidx, E, M);
    k_mm<<<dim3((M + 127) / 128, N / 128), 256, 0, stream>>>(Hb, Wt, HWb, M, N, K);
    k_gather<<<M, 256, 0, stream>>>(HWb, bias, selfmul, offsets, colidx, out, N);
}

// Round 5
// 112.626 us; speedup vs baseline: 1.9595x; 1.1123x over previous
//
#include <hip/hip_runtime.h>
#include <hip/hip_bf16.h>

// n=M=10000 nodes, a=K=512, b=N=256, E=320000 edges.  M must be <= MCAP.

#define NB   128   // edge-partition blocks for hist/fill
#define MCAP 10240
#define DYN_LDS 40960

typedef __attribute__((ext_vector_type(8))) short bf16x8;
typedef __attribute__((ext_vector_type(4))) float f32x4;

__device__ inline ushort f2bf(float f) {
    uint b = __float_as_uint(f);
    return (ushort)((b + 0x7FFFu + ((b >> 16) & 1u)) >> 16);  // RNE
}
__device__ inline float bf2f(ushort u) { return __uint_as_float((uint)u << 16); }

// ---------------------------------------------------------------------------
// MFMA GEMM tile as a device function so its 158 tiles can be co-scheduled
// with the small edge-pipeline kernels (block-range dispatch).
__device__ void mm_tile(int tile, char* smem,
                        const ushort* __restrict__ Hb,
                        const ushort* __restrict__ Wt,
                        ushort* __restrict__ HWb, int M, int N, int K) {
    ushort (*As)[40] = (ushort (*)[40])smem;
    ushort (*Bs)[40] = (ushort (*)[40])(smem + 128 * 40 * 2);
    int mblk = (M + 127) >> 7;
    int m0 = (tile % mblk) * 128, n0 = (tile / mblk) * 128;
    int tid = threadIdx.x;
    int wid = tid >> 6, lane = tid & 63;
    int wm = (wid >> 1) * 64, wn = (wid & 1) * 64;
    int frow = lane & 15, fg = (lane >> 4) * 8;
    f32x4 acc[4][4] = {};
    for (int k0 = 0; k0 < K; k0 += 32) {
        #pragma unroll
        for (int h = 0; h < 2; ++h) {
            int chunk = tid + 256 * h;
            int row = chunk >> 2, kc = (chunk & 3) * 8;
            int gr = m0 + row;
            int4 va = make_int4(0, 0, 0, 0);
            if (gr < M) va = *(const int4*)&Hb[(size_t)gr * K + k0 + kc];
            *(int4*)&As[row][kc] = va;
            int4 vb = *(const int4*)&Wt[(size_t)(n0 + row) * K + k0 + kc];
            *(int4*)&Bs[row][kc] = vb;
        }
        __syncthreads();
        bf16x8 av[4], bv[4];
        #pragma unroll
        for (int i = 0; i < 4; ++i)
            av[i] = *(const bf16x8*)&As[wm + i * 16 + frow][fg];
        #pragma unroll
        for (int j = 0; j < 4; ++j)
            bv[j] = *(const bf16x8*)&Bs[wn + j * 16 + frow][fg];
        #pragma unroll
        for (int i = 0; i < 4; ++i)
            #pragma unroll
            for (int j = 0; j < 4; ++j)
                acc[i][j] = __builtin_amdgcn_mfma_f32_16x16x32_bf16(av[i], bv[j], acc[i][j], 0, 0, 0);
        __syncthreads();
    }
    // C/D map: col=lane&15, row=(lane>>4)*4+rr  [verified m89/m91]
    int orow = (lane >> 4) * 4, ocol = lane & 15;
    #pragma unroll
    for (int i = 0; i < 4; ++i) {
        #pragma unroll
        for (int rr = 0; rr < 4; ++rr) {
            int grow = m0 + wm + i * 16 + orow + rr;
            if (grow < M) {
                #pragma unroll
                for (int j = 0; j < 4; ++j) {
                    int gcol = n0 + wn + j * 16 + ocol;
                    HWb[(size_t)grow * N + gcol] = f2bf(acc[i][j][rr]);
                }
            }
        }
    }
}

// ---------------------------------------------------------------------------
// Fused prelude: q = W @ emb_w (f32-exact); Wt = bf16(W^T); done = 0
__global__ __launch_bounds__(256) void k_prep(const float* __restrict__ W,
                                              const float* __restrict__ emb_w,
                                              float* __restrict__ q,
                                              ushort* __restrict__ Wt,
                                              uint* __restrict__ done,
                                              int K, int N) {
    int b = blockIdx.x;
    int nq = K / 4;
    if (b < nq) {
        int wave = threadIdx.x >> 6;
        int lane = threadIdx.x & 63;
        int k = b * 4 + wave;
        float4 w4 = *(const float4*)&W[(size_t)k * N + lane * 4];
        float4 e4 = *(const float4*)&emb_w[lane * 4];
        float s = w4.x * e4.x + w4.y * e4.y + w4.z * e4.z + w4.w * e4.w;
        #pragma unroll
        for (int d = 32; d; d >>= 1) s += __shfl_down(s, d);
        if (lane == 0) q[k] = s;
    } else if (b < nq + (K / 32) * (N / 32)) {
        __shared__ float ts[32][33];
        int idx = b - nq;
        int k0 = (idx % (K / 32)) * 32;
        int n0 = (idx / (K / 32)) * 32;
        int x = threadIdx.x & 31, y = threadIdx.x >> 5;  // 32x8
        #pragma unroll
        for (int i = 0; i < 4; ++i) {
            int kk = y + i * 8;
            ts[kk][x] = W[(size_t)(k0 + kk) * N + n0 + x];
        }
        __syncthreads();
        #pragma unroll
        for (int i = 0; i < 4; ++i) {
            int nn = y + i * 8;
            Wt[(size_t)(n0 + nn) * K + k0 + x] = f2bf(ts[x][nn]);
        }
    } else {
        if (threadIdx.x == 0) *done = 0;
    }
}

// Fused: Hb = bf16(H)  AND  p[i] = (dot(H[i,:], q) + emb_b) * rv  (f32-exact)
__global__ __launch_bounds__(256) void k_hp(const float* __restrict__ H,
                                            const float* __restrict__ q,
                                            const float* __restrict__ emb_b,
                                            const float* __restrict__ rv,
                                            ushort* __restrict__ Hb,
                                            float* __restrict__ p, int M, int K) {
    int wid = threadIdx.x >> 6, lane = threadIdx.x & 63;
    int i = blockIdx.x * 4 + wid;
    if (i >= M) return;
    const float* h = H + (size_t)i * K;
    float s = 0.f;
    for (int o = lane * 8; o < K; o += 512) {
        float4 a = *(const float4*)&h[o];
        float4 b = *(const float4*)&h[o + 4];
        float4 qa = *(const float4*)&q[o];
        float4 qb = *(const float4*)&q[o + 4];
        s += a.x * qa.x + a.y * qa.y + a.z * qa.z + a.w * qa.w
           + b.x * qb.x + b.y * qb.y + b.z * qb.z + b.w * qb.w;
        ushort u[8] = {f2bf(a.x), f2bf(a.y), f2bf(a.z), f2bf(a.w),
                       f2bf(b.x), f2bf(b.y), f2bf(b.z), f2bf(b.w)};
        *(int4*)&Hb[(size_t)i * K + o] = *(int4*)u;
    }
    #pragma unroll
    for (int d = 32; d; d >>= 1) s += __shfl_down(s, d);
    if (lane == 0) p[i] = (s + emb_b[0]) * rv[0];
}

// ---------------------------------------------------------------------------
// Launch A: blocks [0,NB) = per-block LDS histogram (cross lo16 / self hi16);
//           blocks [NB, ...) = mm tiles [0, mmacnt)
__global__ __launch_bounds__(256) void k_hist_mm(const int* __restrict__ st,
                                                 const float* __restrict__ p,
                                                 uint* __restrict__ parthist,
                                                 const ushort* __restrict__ Hb,
                                                 const ushort* __restrict__ Wt,
                                                 ushort* __restrict__ HWb,
                                                 int E, int M, int N, int K) {
    extern __shared__ char smem[];
    int b = blockIdx.x;
    if (b >= NB) { mm_tile(b - NB, smem, Hb, Wt, HWb, M, N, K); return; }
    uint* h = (uint*)smem;
    for (int i = threadIdx.x; i < M; i += 256) h[i] = 0;
    __syncthreads();
    int epb = (E + NB - 1) / NB;
    int beg = b * epb, end = min(beg + epb, E);
    for (int e = beg + threadIdx.x; e < end; e += 256) {
        int u = st[e], v = st[E + e];
        uint inc = (p[u] > p[v]) ? 1u : (1u << 16);
        atomicAdd(&h[u], inc);
        atomicAdd(&h[v], inc);
    }
    __syncthreads();
    for (int i = threadIdx.x; i < M; i += 256)
        parthist[(size_t)b * M + i] = h[i];
}

// Launch B: blocks [0,nmerge) = per-row merge over NB partials (in-place
// exclusive cross prefix), crosscnt, selfmul; LAST merge block (device
// ticket) also does the global exclusive scan -> offsets.
// Remaining blocks = mm tiles [mmoff, mmoff+cnt).
__global__ __launch_bounds__(256) void k_merge_scan_mm(uint* __restrict__ parthist,
                                                       int* __restrict__ crosscnt,
                                                       float* __restrict__ selfmul,
                                                       int* __restrict__ offsets,
                                                       uint* __restrict__ done,
                                                       const ushort* __restrict__ Hb,
                                                       const ushort* __restrict__ Wt,
                                                       ushort* __restrict__ HWb,
                                                       int M, int N, int K,
                                                       int nmerge, int mmoff) {
    extern __shared__ char smem[];
    int b = blockIdx.x;
    if (b >= nmerge) { mm_tile(b - nmerge + mmoff, smem, Hb, Wt, HWb, M, N, K); return; }
    int r = b * 256 + threadIdx.x;
    if (r < M) {
        uint crun = 0, srun = 0;
        #pragma unroll 8
        for (int bb = 0; bb < NB; ++bb) {
            uint v = parthist[(size_t)bb * M + r];
            parthist[(size_t)bb * M + r] = crun;
            crun += v & 0xFFFFu;
            srun += v >> 16;
        }
        crosscnt[r] = (int)crun;
        selfmul[r] = 1.0f + (float)srun;
    }
    __threadfence();
    __shared__ uint ticket;
    if (threadIdx.x == 0) ticket = atomicAdd(done, 1);
    __syncthreads();
    if (ticket == (uint)(nmerge - 1)) {
        __threadfence();
        __shared__ int s[256];
        int t = threadIdx.x;
        int chunk = (M + 255) / 256;
        int cb = t * chunk;
        int ce = min(cb + chunk, M);
        int sum = 0;
        for (int i = cb; i < ce; ++i) sum += crosscnt[i];
        s[t] = sum;
        __syncthreads();
        for (int d = 1; d < 256; d <<= 1) {
            int val = (t >= d) ? s[t - d] : 0;
            __syncthreads();
            s[t] += val;
            __syncthreads();
        }
        int run = (t == 0) ? 0 : s[t - 1];
        for (int i = cb; i < ce; ++i) {
            offsets[i] = run;
            run += crosscnt[i];
        }
        if (t == 255) offsets[M] = run;
    }
}

// Launch C: blocks [0,NB) = slot assignment (LDS cursors, cross edges only);
//           blocks [NB, ...) = mm tiles [mmoff, ...)
__global__ __launch_bounds__(256) void k_fill_mm(const int* __restrict__ st,
                                                 const float* __restrict__ p,
                                                 const int* __restrict__ offsets,
                                                 const uint* __restrict__ blockbase,
                                                 int* __restrict__ colidx,
                                                 const ushort* __restrict__ Hb,
                                                 const ushort* __restrict__ Wt,
                                                 ushort* __restrict__ HWb,
                                                 int E, int M, int N, int K, int mmoff) {
    extern __shared__ char smem[];
    int b = blockIdx.x;
    if (b >= NB) { mm_tile(b - NB + mmoff, smem, Hb, Wt, HWb, M, N, K); return; }
    int* cur = (int*)smem;
    for (int i = threadIdx.x; i < M; i += 256)
        cur[i] = offsets[i] + (int)blockbase[(size_t)b * M + i];
    __syncthreads();
    int epb = (E + NB - 1) / NB;
    int beg = b * epb, end = min(beg + epb, E);
    for (int e = beg + threadIdx.x; e < end; e += 256) {
        int u = st[e], v = st[E + e];
        if (p[u] > p[v]) {
            int su = atomicAdd(&cur[u], 1);
            colidx[su] = v;
            int sv = atomicAdd(&cur[v], 1);
            colidx[sv] = u;
        }
    }
}

// ---------------------------------------------------------------------------
// out[r,:] = bf2f(HWb[r,:]) * selfmul[r] + bias + sum_j bf2f(HWb[colidx[j],:])
// One WAVE per row; unroll-8 message loop, coalesced colidx load + shfl bcast.
__global__ __launch_bounds__(256) void k_gather(const ushort* __restrict__ HWb,
                                                const float* __restrict__ bias,
                                                const float* __restrict__ selfmul,
                                                const int* __restrict__ offs,
                                                const int* __restrict__ colidx,
                                                float* __restrict__ out, int N, int M) {
    int wid = threadIdx.x >> 6, lane = threadIdx.x & 63;
    int r = blockIdx.x * 4 + wid;
    if (r >= M) return;
    int beg = offs[r], end = offs[r + 1];
    float a0 = 0.f, a1 = 0.f, a2 = 0.f, a3 = 0.f;
    float b0 = 0.f, b1 = 0.f, b2 = 0.f, b3 = 0.f;
    int j = beg;
    for (; j + 8 <= end; j += 8) {
        int c8 = colidx[j + (lane & 7)];
        #pragma unroll
        for (int i = 0; i < 8; i += 2) {
            int ca = __shfl(c8, i, 8);
            int cb = __shfl(c8, i + 1, 8);
            ushort4 ma = *(const ushort4*)&HWb[(size_t)ca * N + lane * 4];
            ushort4 mb = *(const ushort4*)&HWb[(size_t)cb * N + lane * 4];
            a0 += bf2f(ma.x); a1 += bf2f(ma.y); a2 += bf2f(ma.z); a3 += bf2f(ma.w);
            b0 += bf2f(mb.x); b1 += bf2f(mb.y); b2 += bf2f(mb.z); b3 += bf2f(mb.w);
        }
    }
    for (; j < end; ++j) {
        int c = colidx[j];
        ushort4 m = *(const ushort4*)&HWb[(size_t)c * N + lane * 4];
        a0 += bf2f(m.x); a1 += bf2f(m.y); a2 += bf2f(m.z); a3 += bf2f(m.w);
    }
    ushort4 mi = *(const ushort4*)&HWb[(size_t)r * N + lane * 4];
    float4 bi = *(const float4*)&bias[lane * 4];
    float sm = selfmul[r];
    float4 o;
    o.x = bf2f(mi.x) * sm + bi.x + a0 + b0;
    o.y = bf2f(mi.y) * sm + bi.y + a1 + b1;
    o.z = bf2f(mi.z) * sm + bi.z + a2 + b2;
    o.w = bf2f(mi.w) * sm + bi.w + a3 + b3;
    *(float4*)&out[(size_t)r * N + lane * 4] = o;
}

// ---------------------------------------------------------------------------
extern "C" void kernel_launch(void* const* d_in, const int* in_sizes, int n_in,
                              void* d_out, int out_size, void* d_ws, size_t ws_size,
                              hipStream_t stream) {
    const int*   st    = (const int*)d_in[0];
    const float* H     = (const float*)d_in[1];
    const float* W     = (const float*)d_in[2];
    const float* bias  = (const float*)d_in[3];
    const float* emb_w = (const float*)d_in[4];
    const float* emb_b = (const float*)d_in[5];
    const float* rv    = (const float*)d_in[6];
    float* out = (float*)d_out;

    const int E = in_sizes[0] / 2;       // 320000
    const int N = in_sizes[3];           // 256
    const int K = in_sizes[2] / N;       // 512
    const int M = in_sizes[1] / K;       // 10000  (<= MCAP)

    char* ws = (char*)d_ws;
    size_t off = 0;
    auto alloc = [&](size_t bytes) -> char* {
        char* ptr = ws + off;
        off = (off + bytes + 255) & ~(size_t)255;
        return ptr;
    };
    float*  q        = (float*)alloc((size_t)K * 4);
    float*  p        = (float*)alloc((size_t)M * 4);
    ushort* HWb      = (ushort*)alloc((size_t)M * N * 2);
    ushort* Hb       = (ushort*)alloc((size_t)M * K * 2);
    ushort* Wt       = (ushort*)alloc((size_t)K * N * 2);
    uint*   parthist = (uint*)alloc((size_t)NB * M * 4);
    int*    crosscnt = (int*)alloc((size_t)M * 4);
    float*  selfmul  = (float*)alloc((size_t)M * 4);
    int*    offsets  = (int*)alloc((size_t)(M + 1) * 4);
    int*    colidx   = (int*)alloc((size_t)2 * E * 4);
    uint*   done     = (uint*)alloc(256);
    (void)ws_size; (void)n_in; (void)out_size;

    const int tiles  = ((M + 127) / 128) * (N / 128);   // 158
    const int nmerge = (M + 255) / 256;                 // 40
    const int mmA = (tiles * 2) / 5;                    // with hist
    const int mmB = tiles / 4;                          // with merge+scan
    const int mmC = tiles - mmA - mmB;                  // with fill

    k_prep<<<K / 4 + (K / 32) * (N / 32) + 1, 256, 0, stream>>>(W, emb_w, q, Wt, done, K, N);
    k_hp<<<(M + 3) / 4, 256, 0, stream>>>(H, q, emb_b, rv, Hb, p, M, K);
    k_hist_mm<<<NB + mmA, 256, DYN_LDS, stream>>>(st, p, parthist, Hb, Wt, HWb, E, M, N, K);
    k_merge_scan_mm<<<nmerge + mmB, 256, DYN_LDS, stream>>>(parthist, crosscnt, selfmul,
                                                            offsets, done, Hb, Wt, HWb,
                                                            M, N, K, nmerge, mmA);
    k_fill_mm<<<NB + mmC, 256, DYN_LDS, stream>>>(st, p, offsets, parthist, colidx,
                                                  Hb, Wt, HWb, E, M, N, K, mmA + mmB);
    k_gather<<<(M + 3) / 4, 256, 0, stream>>>(HWb, bias, selfmul, offsets, colidx, out, N, M);
}

// Round 6
// 104.839 us; speedup vs baseline: 2.1051x; 1.0743x over previous
//
#include <hip/hip_runtime.h>
#include <hip/hip_bf16.h>

// n=M=10000 nodes, a=K=512, b=N=256, E=320000 edges.  M must be <= MCAP.

#define NB   128   // edge-partition blocks for hist/fill
#define MCAP 10240
#define DYN_LDS 40960

typedef __attribute__((ext_vector_type(8))) short bf16x8;
typedef __attribute__((ext_vector_type(4))) float f32x4;

__device__ inline ushort f2bf(float f) {
    uint b = __float_as_uint(f);
    return (ushort)((b + 0x7FFFu + ((b >> 16) & 1u)) >> 16);  // RNE
}
__device__ inline float bf2f(ushort u) { return __uint_as_float((uint)u << 16); }

// ---------------------------------------------------------------------------
// MFMA GEMM tile as a device function so its 158 tiles can be co-scheduled
// with the small edge-pipeline kernels (block-range dispatch).
__device__ void mm_tile(int tile, char* smem,
                        const ushort* __restrict__ Hb,
                        const ushort* __restrict__ Wt,
                        ushort* __restrict__ HWb, int M, int N, int K) {
    ushort (*As)[40] = (ushort (*)[40])smem;
    ushort (*Bs)[40] = (ushort (*)[40])(smem + 128 * 40 * 2);
    int mblk = (M + 127) >> 7;
    int m0 = (tile % mblk) * 128, n0 = (tile / mblk) * 128;
    int tid = threadIdx.x;
    int wid = tid >> 6, lane = tid & 63;
    int wm = (wid >> 1) * 64, wn = (wid & 1) * 64;
    int frow = lane & 15, fg = (lane >> 4) * 8;
    f32x4 acc[4][4] = {};
    for (int k0 = 0; k0 < K; k0 += 32) {
        #pragma unroll
        for (int h = 0; h < 2; ++h) {
            int chunk = tid + 256 * h;
            int row = chunk >> 2, kc = (chunk & 3) * 8;
            int gr = m0 + row;
            int4 va = make_int4(0, 0, 0, 0);
            if (gr < M) va = *(const int4*)&Hb[(size_t)gr * K + k0 + kc];
            *(int4*)&As[row][kc] = va;
            int4 vb = *(const int4*)&Wt[(size_t)(n0 + row) * K + k0 + kc];
            *(int4*)&Bs[row][kc] = vb;
        }
        __syncthreads();
        bf16x8 av[4], bv[4];
        #pragma unroll
        for (int i = 0; i < 4; ++i)
            av[i] = *(const bf16x8*)&As[wm + i * 16 + frow][fg];
        #pragma unroll
        for (int j = 0; j < 4; ++j)
            bv[j] = *(const bf16x8*)&Bs[wn + j * 16 + frow][fg];
        #pragma unroll
        for (int i = 0; i < 4; ++i)
            #pragma unroll
            for (int j = 0; j < 4; ++j)
                acc[i][j] = __builtin_amdgcn_mfma_f32_16x16x32_bf16(av[i], bv[j], acc[i][j], 0, 0, 0);
        __syncthreads();
    }
    // C/D map: col=lane&15, row=(lane>>4)*4+rr  [verified m89/m91]
    int orow = (lane >> 4) * 4, ocol = lane & 15;
    #pragma unroll
    for (int i = 0; i < 4; ++i) {
        #pragma unroll
        for (int rr = 0; rr < 4; ++rr) {
            int grow = m0 + wm + i * 16 + orow + rr;
            if (grow < M) {
                #pragma unroll
                for (int j = 0; j < 4; ++j) {
                    int gcol = n0 + wn + j * 16 + ocol;
                    HWb[(size_t)grow * N + gcol] = f2bf(acc[i][j][rr]);
                }
            }
        }
    }
}

// ---------------------------------------------------------------------------
// Fused prelude: q = W @ emb_w (f32-exact); Wt = bf16(W^T); done = 0
__global__ __launch_bounds__(256) void k_prep(const float* __restrict__ W,
                                              const float* __restrict__ emb_w,
                                              float* __restrict__ q,
                                              ushort* __restrict__ Wt,
                                              uint* __restrict__ done,
                                              int K, int N) {
    int b = blockIdx.x;
    int nq = K / 4;
    if (b < nq) {
        int wave = threadIdx.x >> 6;
        int lane = threadIdx.x & 63;
        int k = b * 4 + wave;
        float4 w4 = *(const float4*)&W[(size_t)k * N + lane * 4];
        float4 e4 = *(const float4*)&emb_w[lane * 4];
        float s = w4.x * e4.x + w4.y * e4.y + w4.z * e4.z + w4.w * e4.w;
        #pragma unroll
        for (int d = 32; d; d >>= 1) s += __shfl_down(s, d);
        if (lane == 0) q[k] = s;
    } else if (b < nq + (K / 32) * (N / 32)) {
        __shared__ float ts[32][33];
        int idx = b - nq;
        int k0 = (idx % (K / 32)) * 32;
        int n0 = (idx / (K / 32)) * 32;
        int x = threadIdx.x & 31, y = threadIdx.x >> 5;  // 32x8
        #pragma unroll
        for (int i = 0; i < 4; ++i) {
            int kk = y + i * 8;
            ts[kk][x] = W[(size_t)(k0 + kk) * N + n0 + x];
        }
        __syncthreads();
        #pragma unroll
        for (int i = 0; i < 4; ++i) {
            int nn = y + i * 8;
            Wt[(size_t)(n0 + nn) * K + k0 + x] = f2bf(ts[x][nn]);
        }
    } else {
        if (threadIdx.x == 0) *done = 0;
    }
}

// Fused: Hb = bf16(H)  AND  p[i] = (dot(H[i,:], q) + emb_b) * rv  (f32-exact)
__global__ __launch_bounds__(256) void k_hp(const float* __restrict__ H,
                                            const float* __restrict__ q,
                                            const float* __restrict__ emb_b,
                                            const float* __restrict__ rv,
                                            ushort* __restrict__ Hb,
                                            float* __restrict__ p, int M, int K) {
    int wid = threadIdx.x >> 6, lane = threadIdx.x & 63;
    int i = blockIdx.x * 4 + wid;
    if (i >= M) return;
    const float* h = H + (size_t)i * K;
    float s = 0.f;
    for (int o = lane * 8; o < K; o += 512) {
        float4 a = *(const float4*)&h[o];
        float4 b = *(const float4*)&h[o + 4];
        float4 qa = *(const float4*)&q[o];
        float4 qb = *(const float4*)&q[o + 4];
        s += a.x * qa.x + a.y * qa.y + a.z * qa.z + a.w * qa.w
           + b.x * qb.x + b.y * qb.y + b.z * qb.z + b.w * qb.w;
        ushort u[8] = {f2bf(a.x), f2bf(a.y), f2bf(a.z), f2bf(a.w),
                       f2bf(b.x), f2bf(b.y), f2bf(b.z), f2bf(b.w)};
        *(int4*)&Hb[(size_t)i * K + o] = *(int4*)u;
    }
    #pragma unroll
    for (int d = 32; d; d >>= 1) s += __shfl_down(s, d);
    if (lane == 0) p[i] = (s + emb_b[0]) * rv[0];
}

// ---------------------------------------------------------------------------
// Launch A: blocks [0,NB) = per-block LDS histogram (cross lo16 / self hi16);
//           blocks [NB, ...) = mm tiles [0, mmacnt)
__global__ __launch_bounds__(256) void k_hist_mm(const int* __restrict__ st,
                                                 const float* __restrict__ p,
                                                 uint* __restrict__ parthist,
                                                 const ushort* __restrict__ Hb,
                                                 const ushort* __restrict__ Wt,
                                                 ushort* __restrict__ HWb,
                                                 int E, int M, int N, int K) {
    extern __shared__ char smem[];
    int b = blockIdx.x;
    if (b >= NB) { mm_tile(b - NB, smem, Hb, Wt, HWb, M, N, K); return; }
    uint* h = (uint*)smem;
    for (int i = threadIdx.x; i < M; i += 256) h[i] = 0;
    __syncthreads();
    int epb = (E + NB - 1) / NB;
    int beg = b * epb, end = min(beg + epb, E);
    for (int e = beg + threadIdx.x; e < end; e += 256) {
        int u = st[e], v = st[E + e];
        uint inc = (p[u] > p[v]) ? 1u : (1u << 16);
        atomicAdd(&h[u], inc);
        atomicAdd(&h[v], inc);
    }
    __syncthreads();
    for (int i = threadIdx.x; i < M; i += 256)
        parthist[(size_t)b * M + i] = h[i];
}

// Launch B: blocks [0,nmerge) = per-row merge over NB partials (in-place
// exclusive cross prefix), crosscnt, selfmul; LAST merge block (device
// ticket) also does the global exclusive scan -> offsets.
// Remaining blocks = mm tiles [mmoff, mmoff+cnt).
// Merge loads are BATCHED 32-at-a-time into registers (no interleaved
// stores) so the compiler issues them back-to-back instead of a 128-deep
// dependent RMW chain (R5: 43.9 us at 0.7% VALUBusy from exactly that).
__global__ __launch_bounds__(256) void k_merge_scan_mm(uint* __restrict__ parthist,
                                                       int* __restrict__ crosscnt,
                                                       float* __restrict__ selfmul,
                                                       int* __restrict__ offsets,
                                                       uint* __restrict__ done,
                                                       const ushort* __restrict__ Hb,
                                                       const ushort* __restrict__ Wt,
                                                       ushort* __restrict__ HWb,
                                                       int M, int N, int K,
                                                       int nmerge, int mmoff) {
    extern __shared__ char smem[];
    int b = blockIdx.x;
    if (b >= nmerge) { mm_tile(b - nmerge + mmoff, smem, Hb, Wt, HWb, M, N, K); return; }
    int r = b * 256 + threadIdx.x;
    if (r < M) {
        uint crun = 0, srun = 0;
        for (int c = 0; c < NB / 32; ++c) {
            uint vals[32];
            #pragma unroll
            for (int i = 0; i < 32; ++i)
                vals[i] = parthist[(size_t)(c * 32 + i) * M + r];
            #pragma unroll
            for (int i = 0; i < 32; ++i) {
                parthist[(size_t)(c * 32 + i) * M + r] = crun;
                crun += vals[i] & 0xFFFFu;
                srun += vals[i] >> 16;
            }
        }
        crosscnt[r] = (int)crun;
        selfmul[r] = 1.0f + (float)srun;
    }
    __threadfence();
    __shared__ uint ticket;
    if (threadIdx.x == 0) ticket = atomicAdd(done, 1);
    __syncthreads();
    if (ticket == (uint)(nmerge - 1)) {
        __threadfence();
        __shared__ int s[256];
        int t = threadIdx.x;
        int chunk = (M + 255) / 256;
        int cb = t * chunk;
        int ce = min(cb + chunk, M);
        int sum = 0;
        for (int i = cb; i < ce; ++i) sum += crosscnt[i];
        s[t] = sum;
        __syncthreads();
        for (int d = 1; d < 256; d <<= 1) {
            int val = (t >= d) ? s[t - d] : 0;
            __syncthreads();
            s[t] += val;
            __syncthreads();
        }
        int run = (t == 0) ? 0 : s[t - 1];
        for (int i = cb; i < ce; ++i) {
            offsets[i] = run;
            run += crosscnt[i];
        }
        if (t == 255) offsets[M] = run;
    }
}

// Launch C: blocks [0,NB) = slot assignment (LDS cursors, cross edges only);
//           blocks [NB, ...) = mm tiles [mmoff, ...)
__global__ __launch_bounds__(256) void k_fill_mm(const int* __restrict__ st,
                                                 const float* __restrict__ p,
                                                 const int* __restrict__ offsets,
                                                 const uint* __restrict__ blockbase,
                                                 int* __restrict__ colidx,
                                                 const ushort* __restrict__ Hb,
                                                 const ushort* __restrict__ Wt,
                                                 ushort* __restrict__ HWb,
                                                 int E, int M, int N, int K, int mmoff) {
    extern __shared__ char smem[];
    int b = blockIdx.x;
    if (b >= NB) { mm_tile(b - NB + mmoff, smem, Hb, Wt, HWb, M, N, K); return; }
    int* cur = (int*)smem;
    for (int i = threadIdx.x; i < M; i += 256)
        cur[i] = offsets[i] + (int)blockbase[(size_t)b * M + i];
    __syncthreads();
    int epb = (E + NB - 1) / NB;
    int beg = b * epb, end = min(beg + epb, E);
    for (int e = beg + threadIdx.x; e < end; e += 256) {
        int u = st[e], v = st[E + e];
        if (p[u] > p[v]) {
            int su = atomicAdd(&cur[u], 1);
            colidx[su] = v;
            int sv = atomicAdd(&cur[v], 1);
            colidx[sv] = u;
        }
    }
}

// ---------------------------------------------------------------------------
// out[r,:] = bf2f(HWb[r,:]) * selfmul[r] + bias + sum_j bf2f(HWb[colidx[j],:])
// One WAVE per row; unroll-8 message loop, coalesced colidx load + shfl bcast.
__global__ __launch_bounds__(256) void k_gather(const ushort* __restrict__ HWb,
                                                const float* __restrict__ bias,
                                                const float* __restrict__ selfmul,
                                                const int* __restrict__ offs,
                                                const int* __restrict__ colidx,
                                                float* __restrict__ out, int N, int M) {
    int wid = threadIdx.x >> 6, lane = threadIdx.x & 63;
    int r = blockIdx.x * 4 + wid;
    if (r >= M) return;
    int beg = offs[r], end = offs[r + 1];
    float a0 = 0.f, a1 = 0.f, a2 = 0.f, a3 = 0.f;
    float b0 = 0.f, b1 = 0.f, b2 = 0.f, b3 = 0.f;
    int j = beg;
    for (; j + 8 <= end; j += 8) {
        int c8 = colidx[j + (lane & 7)];
        #pragma unroll
        for (int i = 0; i < 8; i += 2) {
            int ca = __shfl(c8, i, 8);
            int cb = __shfl(c8, i + 1, 8);
            ushort4 ma = *(const ushort4*)&HWb[(size_t)ca * N + lane * 4];
            ushort4 mb = *(const ushort4*)&HWb[(size_t)cb * N + lane * 4];
            a0 += bf2f(ma.x); a1 += bf2f(ma.y); a2 += bf2f(ma.z); a3 += bf2f(ma.w);
            b0 += bf2f(mb.x); b1 += bf2f(mb.y); b2 += bf2f(mb.z); b3 += bf2f(mb.w);
        }
    }
    for (; j < end; ++j) {
        int c = colidx[j];
        ushort4 m = *(const ushort4*)&HWb[(size_t)c * N + lane * 4];
        a0 += bf2f(m.x); a1 += bf2f(m.y); a2 += bf2f(m.z); a3 += bf2f(m.w);
    }
    ushort4 mi = *(const ushort4*)&HWb[(size_t)r * N + lane * 4];
    float4 bi = *(const float4*)&bias[lane * 4];
    float sm = selfmul[r];
    float4 o;
    o.x = bf2f(mi.x) * sm + bi.x + a0 + b0;
    o.y = bf2f(mi.y) * sm + bi.y + a1 + b1;
    o.z = bf2f(mi.z) * sm + bi.z + a2 + b2;
    o.w = bf2f(mi.w) * sm + bi.w + a3 + b3;
    *(float4*)&out[(size_t)r * N + lane * 4] = o;
}

// ---------------------------------------------------------------------------
extern "C" void kernel_launch(void* const* d_in, const int* in_sizes, int n_in,
                              void* d_out, int out_size, void* d_ws, size_t ws_size,
                              hipStream_t stream) {
    const int*   st    = (const int*)d_in[0];
    const float* H     = (const float*)d_in[1];
    const float* W     = (const float*)d_in[2];
    const float* bias  = (const float*)d_in[3];
    const float* emb_w = (const float*)d_in[4];
    const float* emb_b = (const float*)d_in[5];
    const float* rv    = (const float*)d_in[6];
    float* out = (float*)d_out;

    const int E = in_sizes[0] / 2;       // 320000
    const int N = in_sizes[3];           // 256
    const int K = in_sizes[2] / N;       // 512
    const int M = in_sizes[1] / K;       // 10000  (<= MCAP)

    char* ws = (char*)d_ws;
    size_t off = 0;
    auto alloc = [&](size_t bytes) -> char* {
        char* ptr = ws + off;
        off = (off + bytes + 255) & ~(size_t)255;
        return ptr;
    };
    float*  q        = (float*)alloc((size_t)K * 4);
    float*  p        = (float*)alloc((size_t)M * 4);
    ushort* HWb      = (ushort*)alloc((size_t)M * N * 2);
    ushort* Hb       = (ushort*)alloc((size_t)M * K * 2);
    ushort* Wt       = (ushort*)alloc((size_t)K * N * 2);
    uint*   parthist = (uint*)alloc((size_t)NB * M * 4);
    int*    crosscnt = (int*)alloc((size_t)M * 4);
    float*  selfmul  = (float*)alloc((size_t)M * 4);
    int*    offsets  = (int*)alloc((size_t)(M + 1) * 4);
    int*    colidx   = (int*)alloc((size_t)2 * E * 4);
    uint*   done     = (uint*)alloc(256);
    (void)ws_size; (void)n_in; (void)out_size;

    const int tiles  = ((M + 127) / 128) * (N / 128);   // 158
    const int nmerge = (M + 255) / 256;                 // 40
    const int mmA = (tiles * 2) / 5;                    // with hist
    const int mmB = tiles / 4;                          // with merge+scan
    const int mmC = tiles - mmA - mmB;                  // with fill

    k_prep<<<K / 4 + (K / 32) * (N / 32) + 1, 256, 0, stream>>>(W, emb_w, q, Wt, done, K, N);
    k_hp<<<(M + 3) / 4, 256, 0, stream>>>(H, q, emb_b, rv, Hb, p, M, K);
    k_hist_mm<<<NB + mmA, 256, DYN_LDS, stream>>>(st, p, parthist, Hb, Wt, HWb, E, M, N, K);
    k_merge_scan_mm<<<nmerge + mmB, 256, DYN_LDS, stream>>>(parthist, crosscnt, selfmul,
                                                            offsets, done, Hb, Wt, HWb,
                                                            M, N, K, nmerge, mmB ? mmA : mmA);
    k_fill_mm<<<NB + mmC, 256, DYN_LDS, stream>>>(st, p, offsets, parthist, colidx,
                                                  Hb, Wt, HWb, E, M, N, K, mmA + mmB);
    k_gather<<<(M + 3) / 4, 256, 0, stream>>>(HWb, bias, selfmul, offsets, colidx, out, N, M);
}